// Round 5
// baseline (459.223 us; speedup 1.0000x reference)
//
#include <hip/hip_runtime.h>
#include <math.h>

#define BLOCK 256
#define GRID  1024

typedef _Float16 half8 __attribute__((ext_vector_type(8)));
typedef float    f32x4 __attribute__((ext_vector_type(4)));

// Output-column permutation: producer writes logical out-feat phi(nt,i) into
// MFMA out-slot (nt,i); then lane (m,q)'s C quads packed pairwise are exactly
// the consumer's B-frag halves (feats kt*32+q*8+j). Activations never leave
// the lane's registers.
__device__ __forceinline__ int phi(int nt, int m) {
    return ((nt >> 1) << 5) + ((m >> 2) << 3) + ((nt & 1) << 2) + (m & 3);
}

// A-operand weight fragment: lane (m,q) holds A[i][k=k0+j] = w[k][nsrc].
__device__ __forceinline__ half8 bfragW(const float* __restrict__ w, int N0,
                                        int nsrc, int k0, int Kreal, bool valid) {
    half8 r;
    #pragma unroll
    for (int j = 0; j < 8; j++) {
        int k = k0 + j;
        float v = (valid && k < Kreal) ? w[k * N0 + nsrc] : 0.f;
        r[j] = (_Float16)v;
    }
    return r;
}

__device__ __forceinline__ half8 packrelu(f32x4 a, f32x4 b) {
    half8 h;
    #pragma unroll
    for (int r = 0; r < 4; r++) {
        h[r]     = (_Float16)fmaxf(a[r], 0.f);
        h[4 + r] = (_Float16)fmaxf(b[r], 0.f);
    }
    return h;
}

__device__ __forceinline__ half8 packraw(f32x4 a, f32x4 b) {
    half8 h;
    #pragma unroll
    for (int r = 0; r < 4; r++) {
        h[r]     = (_Float16)a[r];
        h[4 + r] = (_Float16)b[r];
    }
    return h;
}

__device__ __forceinline__ void sh16(float x, float y, float z, float* e) {
    float xx = x * x, yy = y * y, zz = z * z;
    float xy = x * y, yz = y * z, xz = x * z;
    e[0]  = 0.28209479177387814f;
    e[1]  = -0.48860251190291987f * y;
    e[2]  = 0.48860251190291987f * z;
    e[3]  = -0.48860251190291987f * x;
    e[4]  = 1.0925484305920792f * xy;
    e[5]  = -1.0925484305920792f * yz;
    e[6]  = 0.94617469575756f * zz - 0.31539156525252005f;
    e[7]  = -1.0925484305920792f * xz;
    e[8]  = 0.5462742152960396f * (xx - yy);
    e[9]  = 0.5900435899266435f * y * (3.0f * xx - yy);
    e[10] = 2.890611442640554f * xy * z;
    e[11] = 0.4570457994644657f * y * (4.0f * zz - xx - yy);
    e[12] = 0.3731763325901154f * z * (2.0f * zz - 3.0f * xx - 3.0f * yy);
    e[13] = 0.4570457994644657f * x * (4.0f * zz - xx - yy);
    e[14] = 1.445305721320277f * z * (xx - yy);
    e[15] = 0.5900435899266435f * x * (xx - 3.0f * yy);
}

// Fragment table indices
#define F_SIG0 0    // +nt          (4)
#define F_COL0 4    // +nt*2+kt     (8)
#define F_VIS0 12   // +nt*2+kt     (8)
#define F_SIG1 20   // +nt*2+kt     (4, nt<2)
#define F_VIS1 24   // +kt          (2)
#define F_COL1 26   // +nt*3+kt     (12)
#define F_COL2 38   // +kt          (2)

__device__ half8 build_frag(int f, int m, int q,
                            const float* w_sig0, const float* w_sig1,
                            const float* w_col0, const float* w_col1,
                            const float* w_col2, const float* w_vis0,
                            const float* w_vis1) {
    if (f < 4) {                       // sig0: K=32
        return bfragW(w_sig0, 64, phi(f, m), q * 8, 32, true);
    } else if (f < 12) {               // col0: K=64
        int i = f - 4, nt = i >> 1, kt = i & 1;
        return bfragW(w_col0, 64, phi(nt, m), kt * 32 + q * 8, 64, true);
    } else if (f < 20) {               // vis0: K rows 48..63 zero
        int i = f - 12, nt = i >> 1, kt = i & 1;
        return bfragW(w_vis0, 64, phi(nt, m), kt * 32 + q * 8, 48, true);
    } else if (f < 24) {               // sig1 -> geo, widened 32 cols
        int i = f - 20, nt = i >> 1, kt = i & 1;
        int g = ((m >> 2) << 3) + ((nt & 1) << 2) + (m & 3);
        bool valid = ((m >> 2) < 2) && (g < 15);
        return bfragW(w_sig1, 16, g + 1, kt * 32 + q * 8, 64, valid);
    } else if (f < 26) {               // vis1
        int kt = f - 24;
        return bfragW(w_vis1, 1, 0, kt * 32 + q * 8, 64, m == 0);
    } else if (f < 38) {               // col1: K=79, rows 79..95 zero
        int i = f - 26, nt = i / 3, kt = i % 3;
        return bfragW(w_col1, 64, phi(nt, m), kt * 32 + q * 8, 79, true);
    } else {                           // col2
        int kt = f - 38;
        return bfragW(w_col2, 3, m, kt * 32 + q * 8, 64, m < 3);
    }
}

#define MFMA(A, B, C) __builtin_amdgcn_mfma_f32_16x16x32_f16((A), (B), (C), 0, 0, 0)

__global__ __launch_bounds__(BLOCK, 4) void nerf_lds(
    const float* __restrict__ x_feat,
    const float* __restrict__ dvec,
    const float* __restrict__ lvec,
    const float* __restrict__ w_sig0,   // [32,64]
    const float* __restrict__ w_sig1,   // [64,16]
    const float* __restrict__ w_col0,   // [64,64]
    const float* __restrict__ w_col1,   // [79,64]
    const float* __restrict__ w_col2,   // [64,3]
    const float* __restrict__ w_vis0,   // [48,64]
    const float* __restrict__ w_vis1,   // [64,1]
    float* __restrict__ out, int n)
{
    // Pre-built weight fragments: 40 frags x 64 lanes x 16 B = 40,960 B
    // (exactly 4 blocks/CU). ds_read_b128 at stride-16B -> conflict-free.
    __shared__ half8 sWf[40 * 64];

    const int tid  = threadIdx.x;
    const int wv   = tid >> 6;
    const int lane = tid & 63;
    const int m    = lane & 15;
    const int q    = lane >> 4;

    // Cooperative one-time staging: wave wv builds frags f = wv (mod 4).
    for (int f = wv; f < 40; f += 4)
        sWf[f * 64 + lane] = build_frag(f, m, q, w_sig0, w_sig1, w_col0,
                                        w_col1, w_col2, w_vis0, w_vis1);
    __syncthreads();

    const half8* W = sWf;   // W[f*64 + lane]
    const f32x4 z = {0.f, 0.f, 0.f, 0.f};
    const int ntiles = n >> 6;   // 64 points/block, 16/wave

    int t = blockIdx.x;
    if (t >= ntiles) return;

    // ---- software pipeline: preload iteration-0 inputs ----
    float4 pv0, pv1;
    float pe0, pe1, pe2;
    {
        const int pt = (t << 6) + wv * 16 + m;
        const float4* xv = (const float4*)(x_feat + (size_t)pt * 32 + q * 8);
        pv0 = xv[0]; pv1 = xv[1];
        const float* vvp = (q < 2 ? lvec : dvec) + (size_t)pt * 3;
        pe0 = vvp[0]; pe1 = vvp[1]; pe2 = vvp[2];
    }

    while (t < ntiles) {
        const int pt = (t << 6) + wv * 16 + m;

        // ---- convert current inputs to fragments ----
        half8 fI0;
        fI0[0] = (_Float16)pv0.x; fI0[1] = (_Float16)pv0.y;
        fI0[2] = (_Float16)pv0.z; fI0[3] = (_Float16)pv0.w;
        fI0[4] = (_Float16)pv1.x; fI0[5] = (_Float16)pv1.y;
        fI0[6] = (_Float16)pv1.z; fI0[7] = (_Float16)pv1.w;

        float e[16];
        sh16(pe0, pe1, pe2, e);
        half8 lo, hi;
        #pragma unroll
        for (int u = 0; u < 8; u++) {
            lo[u] = (_Float16)e[u];
            hi[u] = (_Float16)e[8 + u];
        }
        half8 fI1 = (q & 1) ? hi : lo;

        // ---- prefetch next iteration's inputs (hides HBM latency) ----
        const int tn = t + GRID;
        {
            const int tp = (tn < ntiles) ? tn : t;
            const int ptn = (tp << 6) + wv * 16 + m;
            const float4* xv = (const float4*)(x_feat + (size_t)ptn * 32 + q * 8);
            pv0 = xv[0]; pv1 = xv[1];
            const float* vvp = (q < 2 ? lvec : dvec) + (size_t)ptn * 3;
            pe0 = vvp[0]; pe1 = vvp[1]; pe2 = vvp[2];
        }

        // ---- sig0: h = relu(x @ w_sig0), K=32 ----
        f32x4 a0 = z, a1 = z, a2 = z, a3 = z;
        a0 = MFMA(W[(F_SIG0 + 0) * 64 + lane], fI0, a0);
        a1 = MFMA(W[(F_SIG0 + 1) * 64 + lane], fI0, a1);
        a2 = MFMA(W[(F_SIG0 + 2) * 64 + lane], fI0, a2);
        a3 = MFMA(W[(F_SIG0 + 3) * 64 + lane], fI0, a3);
        half8 hK0 = packrelu(a0, a1), hK1 = packrelu(a2, a3);

        // ---- col0: hc = relu([x|lenc|denc] @ w_col0), K=64 ----
        a0 = z; a1 = z; a2 = z; a3 = z;
        a0 = MFMA(W[(F_COL0 + 0) * 64 + lane], fI0, a0);
        a0 = MFMA(W[(F_COL0 + 1) * 64 + lane], fI1, a0);
        a1 = MFMA(W[(F_COL0 + 2) * 64 + lane], fI0, a1);
        a1 = MFMA(W[(F_COL0 + 3) * 64 + lane], fI1, a1);
        a2 = MFMA(W[(F_COL0 + 4) * 64 + lane], fI0, a2);
        a2 = MFMA(W[(F_COL0 + 5) * 64 + lane], fI1, a2);
        a3 = MFMA(W[(F_COL0 + 6) * 64 + lane], fI0, a3);
        a3 = MFMA(W[(F_COL0 + 7) * 64 + lane], fI1, a3);
        half8 cK0 = packrelu(a0, a1), cK1 = packrelu(a2, a3);

        // ---- vis0: hv = relu([x|lenc|0] @ w_vis0) ----
        a0 = z; a1 = z; a2 = z; a3 = z;
        a0 = MFMA(W[(F_VIS0 + 0) * 64 + lane], fI0, a0);
        a0 = MFMA(W[(F_VIS0 + 1) * 64 + lane], fI1, a0);
        a1 = MFMA(W[(F_VIS0 + 2) * 64 + lane], fI0, a1);
        a1 = MFMA(W[(F_VIS0 + 3) * 64 + lane], fI1, a1);
        a2 = MFMA(W[(F_VIS0 + 4) * 64 + lane], fI0, a2);
        a2 = MFMA(W[(F_VIS0 + 5) * 64 + lane], fI1, a2);
        a3 = MFMA(W[(F_VIS0 + 6) * 64 + lane], fI0, a3);
        a3 = MFMA(W[(F_VIS0 + 7) * 64 + lane], fI1, a3);
        half8 vK0 = packrelu(a0, a1), vK1 = packrelu(a2, a3);

        // ---- sig1: geo (no relu), widened 32 cols ----
        a0 = z; a1 = z;
        a0 = MFMA(W[(F_SIG1 + 0) * 64 + lane], hK0, a0);
        a0 = MFMA(W[(F_SIG1 + 1) * 64 + lane], hK1, a0);
        a1 = MFMA(W[(F_SIG1 + 2) * 64 + lane], hK0, a1);
        a1 = MFMA(W[(F_SIG1 + 3) * 64 + lane], hK1, a1);
        half8 gK2 = packraw(a0, a1);

        // ---- vis1 + sigmoid (lands at q==0, r=0) ----
        f32x4 av = z;
        av = MFMA(W[(F_VIS1 + 0) * 64 + lane], vK0, av);
        av = MFMA(W[(F_VIS1 + 1) * 64 + lane], vK1, av);
        float vis = 1.f / (1.f + expf(-av[0]));

        // ---- col1: h2 = relu([hc|geo] @ w_col1), K=96 padded ----
        a0 = z; a1 = z; a2 = z; a3 = z;
        a0 = MFMA(W[(F_COL1 + 0) * 64 + lane], cK0, a0);
        a0 = MFMA(W[(F_COL1 + 1) * 64 + lane], cK1, a0);
        a0 = MFMA(W[(F_COL1 + 2) * 64 + lane], gK2, a0);
        a1 = MFMA(W[(F_COL1 + 3) * 64 + lane], cK0, a1);
        a1 = MFMA(W[(F_COL1 + 4) * 64 + lane], cK1, a1);
        a1 = MFMA(W[(F_COL1 + 5) * 64 + lane], gK2, a1);
        a2 = MFMA(W[(F_COL1 + 6) * 64 + lane], cK0, a2);
        a2 = MFMA(W[(F_COL1 + 7) * 64 + lane], cK1, a2);
        a2 = MFMA(W[(F_COL1 + 8) * 64 + lane], gK2, a2);
        a3 = MFMA(W[(F_COL1 + 9) * 64 + lane], cK0, a3);
        a3 = MFMA(W[(F_COL1 + 10) * 64 + lane], cK1, a3);
        a3 = MFMA(W[(F_COL1 + 11) * 64 + lane], gK2, a3);
        half8 h2K0 = packrelu(a0, a1), h2K1 = packrelu(a2, a3);

        // ---- col2: color = relu(h2 @ w_col2) * vis; rows 0..2 at q==0 ----
        f32x4 ac = z;
        ac = MFMA(W[(F_COL2 + 0) * 64 + lane], h2K0, ac);
        ac = MFMA(W[(F_COL2 + 1) * 64 + lane], h2K1, ac);
        if (q == 0) {
            float* o = out + (size_t)pt * 3;
            o[0] = fmaxf(ac[0], 0.f) * vis;
            o[1] = fmaxf(ac[1], 0.f) * vis;
            o[2] = fmaxf(ac[2], 0.f) * vis;
        }

        t = tn;
    }
}

extern "C" void kernel_launch(void* const* d_in, const int* in_sizes, int n_in,
                              void* d_out, int out_size, void* d_ws, size_t ws_size,
                              hipStream_t stream) {
    const float* x_feat = (const float*)d_in[0];
    const float* dvec   = (const float*)d_in[1];
    const float* lvec   = (const float*)d_in[2];
    const float* w_sig0 = (const float*)d_in[3];
    const float* w_sig1 = (const float*)d_in[4];
    const float* w_col0 = (const float*)d_in[5];
    const float* w_col1 = (const float*)d_in[6];
    const float* w_col2 = (const float*)d_in[7];
    const float* w_vis0 = (const float*)d_in[8];
    const float* w_vis1 = (const float*)d_in[9];
    float* out = (float*)d_out;

    const int n = in_sizes[0] / 32;   // N points (1048576: multiple of 64)
    nerf_lds<<<GRID, BLOCK, 0, stream>>>(x_feat, dvec, lvec,
                                         w_sig0, w_sig1, w_col0, w_col1,
                                         w_col2, w_vis0, w_vis1, out, n);
}

// Round 6
// 334.999 us; speedup vs baseline: 1.3708x; 1.3708x over previous
//
#include <hip/hip_runtime.h>
#include <math.h>

#define BLOCK 256
#define GRID  768   // 3 blocks/CU x 256 CU: persistent grid, load-balanced

typedef _Float16 half8 __attribute__((ext_vector_type(8)));
typedef float    f32x4 __attribute__((ext_vector_type(4)));

// Output-column permutation: producer writes logical out-feat phi(nt,i) into
// MFMA out-slot (nt,i); then lane (m,q)'s C quads packed pairwise are exactly
// the consumer's B-frag halves (feats kt*32+q*8+j). Activations never leave
// the lane's registers.
__device__ __forceinline__ int phi(int nt, int m) {
    return ((nt >> 1) << 5) + ((m >> 2) << 3) + ((nt & 1) << 2) + (m & 3);
}

// A-operand weight fragment: lane (m,q) holds A[i][k=k0+j] = w[k][nsrc].
__device__ __forceinline__ half8 bfragW(const float* __restrict__ w, int N0,
                                        int nsrc, int k0, int Kreal, bool valid) {
    half8 r;
    #pragma unroll
    for (int j = 0; j < 8; j++) {
        int k = k0 + j;
        float v = (valid && k < Kreal) ? w[k * N0 + nsrc] : 0.f;
        r[j] = (_Float16)v;
    }
    return r;
}

__device__ __forceinline__ half8 packrelu(f32x4 a, f32x4 b) {
    half8 h;
    #pragma unroll
    for (int r = 0; r < 4; r++) {
        h[r]     = (_Float16)fmaxf(a[r], 0.f);
        h[4 + r] = (_Float16)fmaxf(b[r], 0.f);
    }
    return h;
}

__device__ __forceinline__ half8 packraw(f32x4 a, f32x4 b) {
    half8 h;
    #pragma unroll
    for (int r = 0; r < 4; r++) {
        h[r]     = (_Float16)a[r];
        h[4 + r] = (_Float16)b[r];
    }
    return h;
}

__device__ __forceinline__ void sh16(float x, float y, float z, float* e) {
    float xx = x * x, yy = y * y, zz = z * z;
    float xy = x * y, yz = y * z, xz = x * z;
    e[0]  = 0.28209479177387814f;
    e[1]  = -0.48860251190291987f * y;
    e[2]  = 0.48860251190291987f * z;
    e[3]  = -0.48860251190291987f * x;
    e[4]  = 1.0925484305920792f * xy;
    e[5]  = -1.0925484305920792f * yz;
    e[6]  = 0.94617469575756f * zz - 0.31539156525252005f;
    e[7]  = -1.0925484305920792f * xz;
    e[8]  = 0.5462742152960396f * (xx - yy);
    e[9]  = 0.5900435899266435f * y * (3.0f * xx - yy);
    e[10] = 2.890611442640554f * xy * z;
    e[11] = 0.4570457994644657f * y * (4.0f * zz - xx - yy);
    e[12] = 0.3731763325901154f * z * (2.0f * zz - 3.0f * xx - 3.0f * yy);
    e[13] = 0.4570457994644657f * x * (4.0f * zz - xx - yy);
    e[14] = 1.445305721320277f * z * (xx - yy);
    e[15] = 0.5900435899266435f * x * (xx - 3.0f * yy);
}

// Fragment table indices
#define F_SIG0 0    // +nt          (4)
#define F_COL0 4    // +nt*2+kt     (8)
#define F_VIS0 12   // +nt*2+kt     (8)
#define F_SIG1 20   // +nt*2+kt     (4, nt<2)
#define F_VIS1 24   // +kt          (2)
#define F_COL1 26   // +nt*3+kt     (12)
#define F_COL2 38   // +kt          (2)

__device__ half8 build_frag(int f, int m, int q,
                            const float* w_sig0, const float* w_sig1,
                            const float* w_col0, const float* w_col1,
                            const float* w_col2, const float* w_vis0,
                            const float* w_vis1) {
    if (f < 4) {                       // sig0: K=32
        return bfragW(w_sig0, 64, phi(f, m), q * 8, 32, true);
    } else if (f < 12) {               // col0: K=64
        int i = f - 4, nt = i >> 1, kt = i & 1;
        return bfragW(w_col0, 64, phi(nt, m), kt * 32 + q * 8, 64, true);
    } else if (f < 20) {               // vis0: K rows 48..63 zero (denc unused)
        int i = f - 12, nt = i >> 1, kt = i & 1;
        return bfragW(w_vis0, 64, phi(nt, m), kt * 32 + q * 8, 48, true);
    } else if (f < 24) {               // sig1 -> geo, widened 32 cols
        int i = f - 20, nt = i >> 1, kt = i & 1;
        int g = ((m >> 2) << 3) + ((nt & 1) << 2) + (m & 3);
        bool valid = ((m >> 2) < 2) && (g < 15);
        return bfragW(w_sig1, 16, g + 1, kt * 32 + q * 8, 64, valid);
    } else if (f < 26) {               // vis1
        int kt = f - 24;
        return bfragW(w_vis1, 1, 0, kt * 32 + q * 8, 64, m == 0);
    } else if (f < 38) {               // col1: K=79, rows 79..95 zero
        int i = f - 26, nt = i / 3, kt = i % 3;
        return bfragW(w_col1, 64, phi(nt, m), kt * 32 + q * 8, 79, true);
    } else {                           // col2
        int kt = f - 38;
        return bfragW(w_col2, 3, m, kt * 32 + q * 8, 64, m < 3);
    }
}

#define MFMA(A, B, C) __builtin_amdgcn_mfma_f32_16x16x32_f16((A), (B), (C), 0, 0, 0)

// __launch_bounds__(256,3): unified VGPR+AGPR cap = 512/3 = 170/wave.
// Round-5 lesson: (256,4) caps at 128 -> compiler spilled ~100-reg working
// set to scratch (FETCH 845 MB). 170 fits the working set with margin.
__global__ __launch_bounds__(BLOCK, 3) void nerf_lds(
    const float* __restrict__ x_feat,
    const float* __restrict__ dvec,
    const float* __restrict__ lvec,
    const float* __restrict__ w_sig0,   // [32,64]
    const float* __restrict__ w_sig1,   // [64,16]
    const float* __restrict__ w_col0,   // [64,64]
    const float* __restrict__ w_col1,   // [79,64]
    const float* __restrict__ w_col2,   // [64,3]
    const float* __restrict__ w_vis0,   // [48,64]
    const float* __restrict__ w_vis1,   // [64,1]
    float* __restrict__ out, int n)
{
    // Pre-built weight fragments: 40 frags x 64 lanes x 16 B = 40,960 B.
    // ds_read_b128 at stride-16B -> conflict-free.
    __shared__ half8 sWf[40 * 64];

    const int tid  = threadIdx.x;
    const int wv   = tid >> 6;
    const int lane = tid & 63;
    const int m    = lane & 15;
    const int q    = lane >> 4;

    for (int f = wv; f < 40; f += 4)
        sWf[f * 64 + lane] = build_frag(f, m, q, w_sig0, w_sig1, w_col0,
                                        w_col1, w_col2, w_vis0, w_vis1);
    __syncthreads();

    const half8* W = sWf;
    const f32x4 z = {0.f, 0.f, 0.f, 0.f};
    const int ntiles = n >> 6;   // 64 points/block-tile, 16/wave

    int t = blockIdx.x;
    if (t >= ntiles) return;

    // ---- software pipeline: preload iteration-0 inputs ----
    float4 pv0, pv1;
    float pe0, pe1, pe2;
    {
        const int pt = (t << 6) + wv * 16 + m;
        const float4* xv = (const float4*)(x_feat + (size_t)pt * 32 + q * 8);
        pv0 = xv[0]; pv1 = xv[1];
        const float* vvp = (q < 2 ? lvec : dvec) + (size_t)pt * 3;
        pe0 = vvp[0]; pe1 = vvp[1]; pe2 = vvp[2];
    }

    while (t < ntiles) {
        const int pt = (t << 6) + wv * 16 + m;

        // ---- current inputs -> fragments ----
        half8 fI0;
        fI0[0] = (_Float16)pv0.x; fI0[1] = (_Float16)pv0.y;
        fI0[2] = (_Float16)pv0.z; fI0[3] = (_Float16)pv0.w;
        fI0[4] = (_Float16)pv1.x; fI0[5] = (_Float16)pv1.y;
        fI0[6] = (_Float16)pv1.z; fI0[7] = (_Float16)pv1.w;

        float e[16];
        sh16(pe0, pe1, pe2, e);
        half8 lo, hi;
        #pragma unroll
        for (int u = 0; u < 8; u++) {
            lo[u] = (_Float16)e[u];
            hi[u] = (_Float16)e[8 + u];
        }
        half8 fI1 = (q & 1) ? hi : lo;

        // ---- prefetch next tile's inputs (in flight across whole body) ----
        const int tn = t + GRID;
        {
            const int tp = (tn < ntiles) ? tn : t;
            const int ptn = (tp << 6) + wv * 16 + m;
            const float4* xv = (const float4*)(x_feat + (size_t)ptn * 32 + q * 8);
            pv0 = xv[0]; pv1 = xv[1];
            const float* vvp = (q < 2 ? lvec : dvec) + (size_t)ptn * 3;
            pe0 = vvp[0]; pe1 = vvp[1]; pe2 = vvp[2];
        }

        // ---- sig0: h = relu(x @ w_sig0), K=32 ----
        f32x4 a0 = z, a1 = z, a2 = z, a3 = z;
        a0 = MFMA(W[(F_SIG0 + 0) * 64 + lane], fI0, a0);
        a1 = MFMA(W[(F_SIG0 + 1) * 64 + lane], fI0, a1);
        a2 = MFMA(W[(F_SIG0 + 2) * 64 + lane], fI0, a2);
        a3 = MFMA(W[(F_SIG0 + 3) * 64 + lane], fI0, a3);
        half8 hK0 = packrelu(a0, a1), hK1 = packrelu(a2, a3);

        // ---- sig1: geo (no relu), widened 32 cols; frees hK ----
        a0 = z; a1 = z;
        a0 = MFMA(W[(F_SIG1 + 0) * 64 + lane], hK0, a0);
        a0 = MFMA(W[(F_SIG1 + 1) * 64 + lane], hK1, a0);
        a1 = MFMA(W[(F_SIG1 + 2) * 64 + lane], hK0, a1);
        a1 = MFMA(W[(F_SIG1 + 3) * 64 + lane], hK1, a1);
        half8 gK2 = packraw(a0, a1);

        // ---- vis0: hv = relu([x|lenc|0] @ w_vis0) ----
        a0 = z; a1 = z; a2 = z; a3 = z;
        a0 = MFMA(W[(F_VIS0 + 0) * 64 + lane], fI0, a0);
        a0 = MFMA(W[(F_VIS0 + 1) * 64 + lane], fI1, a0);
        a1 = MFMA(W[(F_VIS0 + 2) * 64 + lane], fI0, a1);
        a1 = MFMA(W[(F_VIS0 + 3) * 64 + lane], fI1, a1);
        a2 = MFMA(W[(F_VIS0 + 4) * 64 + lane], fI0, a2);
        a2 = MFMA(W[(F_VIS0 + 5) * 64 + lane], fI1, a2);
        a3 = MFMA(W[(F_VIS0 + 6) * 64 + lane], fI0, a3);
        a3 = MFMA(W[(F_VIS0 + 7) * 64 + lane], fI1, a3);
        half8 vK0 = packrelu(a0, a1), vK1 = packrelu(a2, a3);

        // ---- vis1 + sigmoid (lands at q==0, r=0); frees vK ----
        f32x4 av = z;
        av = MFMA(W[(F_VIS1 + 0) * 64 + lane], vK0, av);
        av = MFMA(W[(F_VIS1 + 1) * 64 + lane], vK1, av);
        float vis = 1.f / (1.f + expf(-av[0]));

        // ---- col0: hc = relu([x|lenc|denc] @ w_col0), K=64; frees fI ----
        a0 = z; a1 = z; a2 = z; a3 = z;
        a0 = MFMA(W[(F_COL0 + 0) * 64 + lane], fI0, a0);
        a0 = MFMA(W[(F_COL0 + 1) * 64 + lane], fI1, a0);
        a1 = MFMA(W[(F_COL0 + 2) * 64 + lane], fI0, a1);
        a1 = MFMA(W[(F_COL0 + 3) * 64 + lane], fI1, a1);
        a2 = MFMA(W[(F_COL0 + 4) * 64 + lane], fI0, a2);
        a2 = MFMA(W[(F_COL0 + 5) * 64 + lane], fI1, a2);
        a3 = MFMA(W[(F_COL0 + 6) * 64 + lane], fI0, a3);
        a3 = MFMA(W[(F_COL0 + 7) * 64 + lane], fI1, a3);
        half8 cK0 = packrelu(a0, a1), cK1 = packrelu(a2, a3);

        // ---- col1: h2 = relu([hc|geo] @ w_col1), K=96 padded; frees cK,gK ----
        a0 = z; a1 = z; a2 = z; a3 = z;
        a0 = MFMA(W[(F_COL1 + 0) * 64 + lane], cK0, a0);
        a0 = MFMA(W[(F_COL1 + 1) * 64 + lane], cK1, a0);
        a0 = MFMA(W[(F_COL1 + 2) * 64 + lane], gK2, a0);
        a1 = MFMA(W[(F_COL1 + 3) * 64 + lane], cK0, a1);
        a1 = MFMA(W[(F_COL1 + 4) * 64 + lane], cK1, a1);
        a1 = MFMA(W[(F_COL1 + 5) * 64 + lane], gK2, a1);
        a2 = MFMA(W[(F_COL1 + 6) * 64 + lane], cK0, a2);
        a2 = MFMA(W[(F_COL1 + 7) * 64 + lane], cK1, a2);
        a2 = MFMA(W[(F_COL1 + 8) * 64 + lane], gK2, a2);
        a3 = MFMA(W[(F_COL1 + 9) * 64 + lane], cK0, a3);
        a3 = MFMA(W[(F_COL1 + 10) * 64 + lane], cK1, a3);
        a3 = MFMA(W[(F_COL1 + 11) * 64 + lane], gK2, a3);
        half8 h2K0 = packrelu(a0, a1), h2K1 = packrelu(a2, a3);

        // ---- col2: color = relu(h2 @ w_col2) * vis; rows 0..2 at q==0 ----
        f32x4 ac = z;
        ac = MFMA(W[(F_COL2 + 0) * 64 + lane], h2K0, ac);
        ac = MFMA(W[(F_COL2 + 1) * 64 + lane], h2K1, ac);
        if (q == 0) {
            float* o = out + (size_t)pt * 3;
            o[0] = fmaxf(ac[0], 0.f) * vis;
            o[1] = fmaxf(ac[1], 0.f) * vis;
            o[2] = fmaxf(ac[2], 0.f) * vis;
        }

        t = tn;
    }
}

extern "C" void kernel_launch(void* const* d_in, const int* in_sizes, int n_in,
                              void* d_out, int out_size, void* d_ws, size_t ws_size,
                              hipStream_t stream) {
    const float* x_feat = (const float*)d_in[0];
    const float* dvec   = (const float*)d_in[1];
    const float* lvec   = (const float*)d_in[2];
    const float* w_sig0 = (const float*)d_in[3];
    const float* w_sig1 = (const float*)d_in[4];
    const float* w_col0 = (const float*)d_in[5];
    const float* w_col1 = (const float*)d_in[6];
    const float* w_col2 = (const float*)d_in[7];
    const float* w_vis0 = (const float*)d_in[8];
    const float* w_vis1 = (const float*)d_in[9];
    float* out = (float*)d_out;

    const int n = in_sizes[0] / 32;   // N points (1048576: multiple of 64)
    nerf_lds<<<GRID, BLOCK, 0, stream>>>(x_feat, dvec, lvec,
                                         w_sig0, w_sig1, w_col0, w_col1,
                                         w_col2, w_vis0, w_vis1, out, n);
}